// Round 1
// baseline (4741.512 us; speedup 1.0000x reference)
//
#include <hip/hip_runtime.h>
#include <math.h>

#define NROWS 131072
#define TM 32
#define NBLK (NROWS / TM)      // 4096
#define NB 10                  // NUM_BINS
#define PPF 29                 // 3*NB-1 params per transform feature
#define PDIM 928               // 32 * PPF
#define HID 512
#define KB 8                   // W2 k-rows per LDS chunk
#define NCHUNK (HID / KB)      // 64
#define CHUNK_F4 (KB * PDIM / 4) // 1856

__device__ __forceinline__ float softplusf(float v) {
    // stable softplus matching jax.nn.softplus
    return fmaxf(v, 0.f) + log1pf(expf(-fabsf(v)));
}

__global__ __launch_bounds__(256) void flow_fused(
    const float* __restrict__ x,
    const float* __restrict__ W1,
    const float* __restrict__ b1,
    const float* __restrict__ W2,
    const float* __restrict__ b2,
    float* __restrict__ out,
    float* __restrict__ lad_out,
    float* __restrict__ ot_out)
{
    __shared__ float sm_x[TM][64];          // 8 KB
    __shared__ float sm_h[TM][HID];         // 64 KB
    __shared__ float sm_w2[2][KB * PDIM];   // 58 KB (double buffer)

    const int tid = threadIdx.x;
    const int row0 = blockIdx.x * TM;

    // ---- issue W2 chunk-0 loads as early as possible (latency hiding) ----
    const float4* w2v = (const float4*)W2;
    float4 pre[8];
    #pragma unroll
    for (int q = 0; q < 8; ++q) {
        int idx = tid + q * 256;
        if (idx < CHUNK_F4) pre[q] = w2v[idx];
    }

    // ---- phase 0: load x tile to LDS; write identity (odd) output cols ----
    {
        const float4* xv = (const float4*)(x + (size_t)row0 * 64);
        #pragma unroll
        for (int it = 0; it < 2; ++it) {
            int q = tid + it * 256;          // float4 index 0..511
            float4 v = xv[q];
            int r = q >> 4;
            int c = (q & 15) * 4;
            *(float4*)&sm_x[r][c] = v;
            size_t ob = ((size_t)(row0 + r)) * 64 + c;
            out[ob + 1] = v.y;               // odd cols = identity passthrough
            out[ob + 3] = v.w;
        }
    }
    __syncthreads();

    // ---- phase 1: h = relu(ident @ W1 + b1), ident[r][k] = x[r][2k+1] ----
    {
        const int rg = tid >> 6;   // 0..3 -> rows rg*8..rg*8+7
        const int cg = tid & 63;   // 0..63 -> cols cg*8..cg*8+7
        float hacc[8][8];
        #pragma unroll
        for (int a = 0; a < 8; ++a)
            #pragma unroll
            for (int b = 0; b < 8; ++b) hacc[a][b] = 0.f;
        const float* w1p = W1 + cg * 8;
        for (int k = 0; k < 32; ++k) {
            float4 wa = *(const float4*)(w1p + k * HID);
            float4 wb = *(const float4*)(w1p + k * HID + 4);
            #pragma unroll
            for (int rr = 0; rr < 8; ++rr) {
                float iv = sm_x[rg * 8 + rr][2 * k + 1];  // broadcast read
                hacc[rr][0] = fmaf(iv, wa.x, hacc[rr][0]);
                hacc[rr][1] = fmaf(iv, wa.y, hacc[rr][1]);
                hacc[rr][2] = fmaf(iv, wa.z, hacc[rr][2]);
                hacc[rr][3] = fmaf(iv, wa.w, hacc[rr][3]);
                hacc[rr][4] = fmaf(iv, wb.x, hacc[rr][4]);
                hacc[rr][5] = fmaf(iv, wb.y, hacc[rr][5]);
                hacc[rr][6] = fmaf(iv, wb.z, hacc[rr][6]);
                hacc[rr][7] = fmaf(iv, wb.w, hacc[rr][7]);
            }
        }
        float4 ba = *(const float4*)(b1 + cg * 8);
        float4 bb = *(const float4*)(b1 + cg * 8 + 4);
        #pragma unroll
        for (int rr = 0; rr < 8; ++rr) {
            int r = rg * 8 + rr;
            float4 v0, v1;
            v0.x = fmaxf(hacc[rr][0] + ba.x, 0.f);
            v0.y = fmaxf(hacc[rr][1] + ba.y, 0.f);
            v0.z = fmaxf(hacc[rr][2] + ba.z, 0.f);
            v0.w = fmaxf(hacc[rr][3] + ba.w, 0.f);
            v1.x = fmaxf(hacc[rr][4] + bb.x, 0.f);
            v1.y = fmaxf(hacc[rr][5] + bb.y, 0.f);
            v1.z = fmaxf(hacc[rr][6] + bb.z, 0.f);
            v1.w = fmaxf(hacc[rr][7] + bb.w, 0.f);
            *(float4*)&sm_h[r][cg * 8]     = v0;
            *(float4*)&sm_h[r][cg * 8 + 4] = v1;
        }
    }
    __syncthreads();

    // write W2 chunk 0 into LDS buffer 0
    #pragma unroll
    for (int q = 0; q < 8; ++q) {
        int idx = tid + q * 256;
        if (idx < CHUNK_F4) *(float4*)&sm_w2[0][idx * 4] = pre[q];
    }
    __syncthreads();

    // ---- phase 2: params = h @ W2 + b2 (K=512), fused spline epilogue ----
    const int dtr = tid & 31;   // transform-feature index (lane-parallel)
    const int rg2 = tid >> 5;   // 0..7 -> rows rg2*4 .. rg2*4+3
    const int r0 = rg2 * 4;

    float acc[4][PPF];
    #pragma unroll
    for (int i = 0; i < 4; ++i)
        #pragma unroll
        for (int j = 0; j < PPF; ++j) acc[i][j] = 0.f;

    for (int c = 0; c < NCHUNK; ++c) {
        // T14: issue next chunk's global loads before compute
        if (c + 1 < NCHUNK) {
            const float4* src = w2v + (size_t)(c + 1) * CHUNK_F4;
            #pragma unroll
            for (int q = 0; q < 8; ++q) {
                int idx = tid + q * 256;
                if (idx < CHUNK_F4) pre[q] = src[idx];
            }
        }
        const float* buf = sm_w2[c & 1];
        const int k0 = c * KB;
        #pragma unroll 2
        for (int kk = 0; kk < KB; ++kk) {
            // lanes read stride-29 floats: 29 mod 32 coprime -> conflict-free
            const float* wrow = buf + kk * PDIM + dtr * PPF;
            float h0 = sm_h[r0 + 0][k0 + kk];
            float h1 = sm_h[r0 + 1][k0 + kk];
            float h2 = sm_h[r0 + 2][k0 + kk];
            float h3 = sm_h[r0 + 3][k0 + kk];
            #pragma unroll
            for (int j = 0; j < PPF; ++j) {
                float w = wrow[j];
                acc[0][j] = fmaf(h0, w, acc[0][j]);
                acc[1][j] = fmaf(h1, w, acc[1][j]);
                acc[2][j] = fmaf(h2, w, acc[2][j]);
                acc[3][j] = fmaf(h3, w, acc[3][j]);
            }
        }
        __syncthreads();   // all waves done reading buf (c&1)
        if (c + 1 < NCHUNK) {
            float* nb_ = sm_w2[(c + 1) & 1];
            #pragma unroll
            for (int q = 0; q < 8; ++q) {
                int idx = tid + q * 256;
                if (idx < CHUNK_F4) *(float4*)&nb_[idx * 4] = pre[q];
            }
            __syncthreads();
        }
    }

    // bias
    {
        const float* b2p = b2 + dtr * PPF;
        float bv[PPF];
        #pragma unroll
        for (int j = 0; j < PPF; ++j) bv[j] = b2p[j];
        #pragma unroll
        for (int i = 0; i < 4; ++i)
            #pragma unroll
            for (int j = 0; j < PPF; ++j) acc[i][j] += bv[j];
    }

    const float SCALE = 0.04419417382415922f;  // 1/sqrt(512)
    float lad_a[4], ot_a[4];
    #pragma unroll
    for (int i = 0; i < 4; ++i) {
        const int row = r0 + i;
        const float xv = sm_x[row][2 * dtr];

        // --- widths: softmax -> min-width affine -> cumsum -> [-1,1] ---
        float uw[NB];
        #pragma unroll
        for (int j = 0; j < NB; ++j) uw[j] = acc[i][j] * SCALE;
        float mw = uw[0];
        #pragma unroll
        for (int j = 1; j < NB; ++j) mw = fmaxf(mw, uw[j]);
        float sw = 0.f;
        #pragma unroll
        for (int j = 0; j < NB; ++j) { uw[j] = expf(uw[j] - mw); sw += uw[j]; }
        float invw = 1.f / sw;
        float cw[NB + 1];
        cw[0] = -1.f;
        float cum = 0.f;
        #pragma unroll
        for (int j = 0; j < NB; ++j) {
            cum += 0.001f + 0.99f * uw[j] * invw;
            cw[j + 1] = 2.f * cum - 1.f;
        }
        cw[NB] = 1.f;

        // --- heights ---
        float uh[NB];
        #pragma unroll
        for (int j = 0; j < NB; ++j) uh[j] = acc[i][NB + j] * SCALE;
        float mh = uh[0];
        #pragma unroll
        for (int j = 1; j < NB; ++j) mh = fmaxf(mh, uh[j]);
        float sh = 0.f;
        #pragma unroll
        for (int j = 0; j < NB; ++j) { uh[j] = expf(uh[j] - mh); sh += uh[j]; }
        float invh = 1.f / sh;
        float ch[NB + 1];
        ch[0] = -1.f;
        float cumh = 0.f;
        #pragma unroll
        for (int j = 0; j < NB; ++j) {
            cumh += 0.001f + 0.99f * uh[j] * invh;
            ch[j + 1] = 2.f * cumh - 1.f;
        }
        ch[NB] = 1.f;

        // --- derivatives (padded ends -> exactly 1.0) ---
        float dv[NB + 1];
        dv[0] = 1.0f;
        dv[NB] = 1.0f;
        #pragma unroll
        for (int j = 0; j < NB - 1; ++j)
            dv[j + 1] = 0.001f + softplusf(acc[i][2 * NB + j]);

        // --- bin search (select-scan, no runtime array indexing) ---
        float xc = fminf(fmaxf(xv, -1.f), 1.f);
        int idx = 0;
        #pragma unroll
        for (int j = 1; j <= NB - 1; ++j) idx += (xc >= cw[j]) ? 1 : 0;
        float in_cw = cw[0], cwn = cw[1];
        float in_ch = ch[0], chn = ch[1];
        float dk = dv[0], dk1 = dv[1];
        #pragma unroll
        for (int j = 1; j <= NB - 1; ++j) {
            bool cnd = (idx >= j);
            in_cw = cnd ? cw[j] : in_cw;
            cwn   = cnd ? cw[j + 1] : cwn;
            in_ch = cnd ? ch[j] : in_ch;
            chn   = cnd ? ch[j + 1] : chn;
            dk    = cnd ? dv[j] : dk;
            dk1   = cnd ? dv[j + 1] : dk1;
        }
        float in_w  = cwn - in_cw;
        float in_h  = chn - in_ch;
        float delta = in_h / in_w;
        float th    = (xc - in_cw) / in_w;
        float t1m   = th * (1.f - th);
        float th2   = th * th;
        float numer = in_h * (delta * th2 + dk * t1m);
        float denom = delta + (dk + dk1 - 2.f * delta) * t1m;
        float y     = in_ch + numer / denom;
        float omt   = 1.f - th;
        float dnum  = delta * delta * (dk1 * th2 + 2.f * delta * t1m + dk * omt * omt);
        float lad   = logf(dnum) - 2.f * logf(denom);

        bool inside = (xv >= -1.f) && (xv <= 1.f);
        float yo = inside ? y : xv;
        out[((size_t)(row0 + row)) * 64 + 2 * dtr] = yo;
        lad_a[i] = inside ? lad : 0.f;
        float dd = xv - yo;
        ot_a[i] = dd * dd;
    }

    // --- reduce over the 32 transform features (lanes 0..31 of each half) ---
    #pragma unroll
    for (int m = 1; m < 32; m <<= 1) {
        #pragma unroll
        for (int i = 0; i < 4; ++i) {
            lad_a[i] += __shfl_xor(lad_a[i], m);
            ot_a[i]  += __shfl_xor(ot_a[i], m);
        }
    }
    if (dtr < 4) {
        float lv = lad_a[0], ov = ot_a[0];
        if (dtr == 1) { lv = lad_a[1]; ov = ot_a[1]; }
        else if (dtr == 2) { lv = lad_a[2]; ov = ot_a[2]; }
        else if (dtr == 3) { lv = lad_a[3]; ov = ot_a[3]; }
        int row = row0 + r0 + dtr;
        lad_out[row] = lv;
        ot_out[row]  = ov;
    }
}

extern "C" void kernel_launch(void* const* d_in, const int* in_sizes, int n_in,
                              void* d_out, int out_size, void* d_ws, size_t ws_size,
                              hipStream_t stream) {
    const float* x  = (const float*)d_in[0];
    const float* W1 = (const float*)d_in[1];
    const float* b1 = (const float*)d_in[2];
    const float* W2 = (const float*)d_in[3];
    const float* b2 = (const float*)d_in[4];
    float* out = (float*)d_out;
    float* lad = out + (size_t)NROWS * 64;
    float* otc = lad + NROWS;
    hipLaunchKernelGGL(flow_fused, dim3(NBLK), dim3(256), 0, stream,
                       x, W1, b1, W2, b2, out, lad, otc);
}

// Round 2
// 491.745 us; speedup vs baseline: 9.6422x; 9.6422x over previous
//
#include <hip/hip_runtime.h>
#include <math.h>

#define NROWS 131072
#define BM 64
#define NBLK (NROWS / BM)        // 2048
#define NB 10
#define PPF 29
#define NRAW 928
#define NPAD 1024
#define HID 512
#define THREADS 512

typedef _Float16 half8 __attribute__((ext_vector_type(8)));
typedef _Float16 half4v __attribute__((ext_vector_type(4)));
typedef float f32x4 __attribute__((ext_vector_type(4)));

// ws layout: W2T fp16 [NPAD][HID] at 0 (1 MB); W1T fp16 [HID][32] after it (32 KB)
#define W1T_OFF (NPAD * HID * 2)

// LDS layout (union): h fp16 [64 rows][64 slots*16B] at 0 (64KB),
// B chunk dbuf at 64KB/96KB (32KB each). P (params f32 [32][937]) reuses offset 0.
#define LDS_B0 65536
#define LDS_B1 98304
#define LDS_TOTAL 131072
#define PSTR 937

__global__ __launch_bounds__(256) void prep_w2(const float* __restrict__ W2,
                                               _Float16* __restrict__ W2T) {
    __shared__ float tile[32][33];
    const int kt = blockIdx.x >> 5;      // 0..15 (k tile)
    const int nt = blockIdx.x & 31;      // 0..31 (n tile)
    const int t = threadIdx.x;
    const int j = t & 31;                // n_local
    const int i0 = t >> 5;               // 0..7
    #pragma unroll
    for (int q = 0; q < 4; ++q) {
        int i = i0 + q * 8;              // k_local
        int n = nt * 32 + j;
        float v = 0.f;
        if (n < NRAW) v = W2[(size_t)(kt * 32 + i) * NRAW + n];
        tile[i][j] = v;
    }
    __syncthreads();
    const int n_l = t >> 3;              // 0..31
    const int k_l = (t & 7) * 4;         // 0..28
    half4v o;
    o[0] = (_Float16)tile[k_l + 0][n_l];
    o[1] = (_Float16)tile[k_l + 1][n_l];
    o[2] = (_Float16)tile[k_l + 2][n_l];
    o[3] = (_Float16)tile[k_l + 3][n_l];
    *(half4v*)&W2T[(size_t)(nt * 32 + n_l) * HID + kt * 32 + k_l] = o;
}

__global__ __launch_bounds__(256) void prep_w1(const float* __restrict__ W1,
                                               _Float16* __restrict__ W1T) {
    int idx = blockIdx.x * 256 + threadIdx.x;   // 0..16383
    int n = idx >> 5, k = idx & 31;
    W1T[n * 32 + k] = (_Float16)W1[k * HID + n];
}

__device__ __forceinline__ float softplusf(float v) {
    return fmaxf(v, 0.f) + log1pf(expf(-fabsf(v)));
}

__device__ __forceinline__ void rqs_one(const float* p, float xv, float& yo,
                                        float& lad_o, float& ot_o) {
    const float SCALE = 0.04419417382415922f;  // 1/sqrt(512)
    float uw[NB];
    #pragma unroll
    for (int j = 0; j < NB; ++j) uw[j] = p[j] * SCALE;
    float mw = uw[0];
    #pragma unroll
    for (int j = 1; j < NB; ++j) mw = fmaxf(mw, uw[j]);
    float sw = 0.f;
    #pragma unroll
    for (int j = 0; j < NB; ++j) { uw[j] = expf(uw[j] - mw); sw += uw[j]; }
    float invw = 1.f / sw;
    float cw[NB + 1];
    cw[0] = -1.f;
    float cum = 0.f;
    #pragma unroll
    for (int j = 0; j < NB; ++j) {
        cum += 0.001f + 0.99f * uw[j] * invw;
        cw[j + 1] = 2.f * cum - 1.f;
    }
    cw[NB] = 1.f;

    float uh[NB];
    #pragma unroll
    for (int j = 0; j < NB; ++j) uh[j] = p[NB + j] * SCALE;
    float mh = uh[0];
    #pragma unroll
    for (int j = 1; j < NB; ++j) mh = fmaxf(mh, uh[j]);
    float sh = 0.f;
    #pragma unroll
    for (int j = 0; j < NB; ++j) { uh[j] = expf(uh[j] - mh); sh += uh[j]; }
    float invh = 1.f / sh;
    float ch[NB + 1];
    ch[0] = -1.f;
    float cumh = 0.f;
    #pragma unroll
    for (int j = 0; j < NB; ++j) {
        cumh += 0.001f + 0.99f * uh[j] * invh;
        ch[j + 1] = 2.f * cumh - 1.f;
    }
    ch[NB] = 1.f;

    float dv[NB + 1];
    dv[0] = 1.0f;
    dv[NB] = 1.0f;
    #pragma unroll
    for (int j = 0; j < NB - 1; ++j) dv[j + 1] = 0.001f + softplusf(p[2 * NB + j]);

    float xc = fminf(fmaxf(xv, -1.f), 1.f);
    int idx = 0;
    #pragma unroll
    for (int j = 1; j <= NB - 1; ++j) idx += (xc >= cw[j]) ? 1 : 0;
    float in_cw = cw[0], cwn = cw[1];
    float in_ch = ch[0], chn = ch[1];
    float dk = dv[0], dk1 = dv[1];
    #pragma unroll
    for (int j = 1; j <= NB - 1; ++j) {
        bool cnd = (idx >= j);
        in_cw = cnd ? cw[j] : in_cw;
        cwn   = cnd ? cw[j + 1] : cwn;
        in_ch = cnd ? ch[j] : in_ch;
        chn   = cnd ? ch[j + 1] : chn;
        dk    = cnd ? dv[j] : dk;
        dk1   = cnd ? dv[j + 1] : dk1;
    }
    float in_w  = cwn - in_cw;
    float in_h  = chn - in_ch;
    float delta = in_h / in_w;
    float th    = (xc - in_cw) / in_w;
    float t1m   = th * (1.f - th);
    float th2   = th * th;
    float numer = in_h * (delta * th2 + dk * t1m);
    float denom = delta + (dk + dk1 - 2.f * delta) * t1m;
    float y     = in_ch + numer / denom;
    float omt   = 1.f - th;
    float dnum  = delta * delta * (dk1 * th2 + 2.f * delta * t1m + dk * omt * omt);
    float lad   = logf(dnum) - 2.f * logf(denom);

    bool inside = (xv >= -1.f) && (xv <= 1.f);
    yo = inside ? y : xv;
    lad_o = inside ? lad : 0.f;
    float dd = xv - yo;
    ot_o = dd * dd;
}

__global__ __launch_bounds__(THREADS, 2) void flow_main(
    const float* __restrict__ x,
    const float* __restrict__ b1,
    const float* __restrict__ b2,
    const _Float16* __restrict__ W2T,
    const _Float16* __restrict__ W1T,
    float* __restrict__ out,
    float* __restrict__ lad_out,
    float* __restrict__ ot_out)
{
    __shared__ __align__(16) char smem[LDS_TOTAL];
    __shared__ float sb2[NRAW];
    const int tid = threadIdx.x;
    const int w   = tid >> 6;      // wave 0..7
    const int l   = tid & 63;
    const int l15 = l & 15;
    const int g   = l >> 4;        // k-group 0..3
    const int row0 = blockIdx.x * BM;

    // ---- phase A: copy x -> out (odd cols = identity; even cols fixed later) ----
    {
        const float4* xv = (const float4*)(x + (size_t)row0 * 64);
        float4* ov = (float4*)(out + (size_t)row0 * 64);
        ov[tid] = xv[tid];
        ov[tid + 512] = xv[tid + 512];
    }
    sb2[tid] = b2[tid];
    if (tid < NRAW - 512) sb2[tid + 512] = b2[tid + 512];

    // ---- issue chunk(0,0) loads (T14 issue-early) ----
    float4 st[4];
    #pragma unroll
    for (int q = 0; q < 4; ++q) {
        int s = tid + 512 * q;
        int nl = s >> 2, gg = s & 3;
        st[q] = *(const float4*)((const char*)W2T + (size_t)nl * (HID * 2) + gg * 16);
    }

    // ---- GEMM1: h = relu(ident @ W1 + b1), via MFMA, K=32 in one step ----
    {
        const int mt1 = w >> 1;            // m-tile 0..3
        const int nbase = (w & 1) * 256;   // hidden-col base
        half8 a1;
        {
            const float4* xr = (const float4*)(x + (size_t)(row0 + mt1 * 16 + l15) * 64 + g * 16);
            float4 q0 = xr[0], q1 = xr[1], q2 = xr[2], q3 = xr[3];
            a1[0] = (_Float16)q0.y; a1[1] = (_Float16)q0.w;
            a1[2] = (_Float16)q1.y; a1[3] = (_Float16)q1.w;
            a1[4] = (_Float16)q2.y; a1[5] = (_Float16)q2.w;
            a1[6] = (_Float16)q3.y; a1[7] = (_Float16)q3.w;
        }
        #pragma unroll
        for (int j = 0; j < 16; ++j) {
            int n = nbase + j * 16 + l15;
            half8 bf = *(const half8*)((const char*)W1T + (size_t)n * 64 + g * 16);
            f32x4 c = {0.f, 0.f, 0.f, 0.f};
            c = __builtin_amdgcn_mfma_f32_16x16x32_f16(a1, bf, c, 0, 0, 0);
            float bias = b1[n];
            int srow_base = mt1 * 16 + g * 4;
            int sslot = n >> 3;
            #pragma unroll
            for (int r = 0; r < 4; ++r) {
                float hv = fmaxf(c[r] + bias, 0.f);
                int row = srow_base + r;
                int addr = row * 1024 + ((sslot ^ (row & 7)) << 4) + (n & 7) * 2;
                *(_Float16*)(smem + addr) = (_Float16)hv;
            }
        }
    }
    // write chunk(0,0) -> buf0 (swizzled, conflict-free pattern)
    #pragma unroll
    for (int q = 0; q < 4; ++q) {
        int s = tid + 512 * q;
        int nl = s >> 2, gg = s & 3;
        int line = nl >> 1;
        int pos = (gg + 4 * (nl & 1)) ^ (line & 7);
        *(float4*)(smem + LDS_B0 + line * 128 + pos * 16) = st[q];
    }
    __syncthreads();

    // ---- GEMM2 main loop: K=512 (16 ksteps), N=1024 in 2 halves, true dbuf ----
    f32x4 acc[4][8];
    #pragma unroll
    for (int mt = 0; mt < 4; ++mt)
        #pragma unroll
        for (int i = 0; i < 8; ++i) acc[mt][i] = (f32x4){0.f, 0.f, 0.f, 0.f};

    const int bn0 = w * 16 + l15;   // per-lane n_loc base (same both halves)

    for (int ks = 0; ks < 16; ++ks) {
        // issue loads: chunk(ks, half1)
        #pragma unroll
        for (int q = 0; q < 4; ++q) {
            int s = tid + 512 * q;
            int nl = s >> 2, gg = s & 3;
            st[q] = *(const float4*)((const char*)W2T +
                     (size_t)(512 + nl) * (HID * 2) + ks * 64 + gg * 16);
        }
        // A-frags for this kstep (reused by both halves)
        half8 af[4];
        #pragma unroll
        for (int mt = 0; mt < 4; ++mt) {
            int row = mt * 16 + l15;
            int sslot = ks * 4 + g;
            af[mt] = *(const half8*)(smem + row * 1024 + ((sslot ^ (row & 7)) << 4));
        }
        // half0 from buf0
        #pragma unroll
        for (int i2 = 0; i2 < 4; ++i2) {
            int nloc = bn0 + i2 * 128;
            int line = nloc >> 1;
            int pos = (g + 4 * (nloc & 1)) ^ (line & 7);
            half8 bf = *(const half8*)(smem + LDS_B0 + line * 128 + pos * 16);
            acc[0][i2] = __builtin_amdgcn_mfma_f32_16x16x32_f16(af[0], bf, acc[0][i2], 0, 0, 0);
            acc[1][i2] = __builtin_amdgcn_mfma_f32_16x16x32_f16(af[1], bf, acc[1][i2], 0, 0, 0);
            acc[2][i2] = __builtin_amdgcn_mfma_f32_16x16x32_f16(af[2], bf, acc[2][i2], 0, 0, 0);
            acc[3][i2] = __builtin_amdgcn_mfma_f32_16x16x32_f16(af[3], bf, acc[3][i2], 0, 0, 0);
        }
        // write chunk(ks, half1) -> buf1
        #pragma unroll
        for (int q = 0; q < 4; ++q) {
            int s = tid + 512 * q;
            int nl = s >> 2, gg = s & 3;
            int line = nl >> 1;
            int pos = (gg + 4 * (nl & 1)) ^ (line & 7);
            *(float4*)(smem + LDS_B1 + line * 128 + pos * 16) = st[q];
        }
        __syncthreads();

        // issue loads: chunk(ks+1, half0)
        if (ks < 15) {
            #pragma unroll
            for (int q = 0; q < 4; ++q) {
                int s = tid + 512 * q;
                int nl = s >> 2, gg = s & 3;
                st[q] = *(const float4*)((const char*)W2T +
                         (size_t)nl * (HID * 2) + (ks + 1) * 64 + gg * 16);
            }
        }
        // half1 from buf1
        #pragma unroll
        for (int i2 = 0; i2 < 4; ++i2) {
            int nloc = bn0 + i2 * 128;
            int line = nloc >> 1;
            int pos = (g + 4 * (nloc & 1)) ^ (line & 7);
            half8 bf = *(const half8*)(smem + LDS_B1 + line * 128 + pos * 16);
            acc[0][4 + i2] = __builtin_amdgcn_mfma_f32_16x16x32_f16(af[0], bf, acc[0][4 + i2], 0, 0, 0);
            acc[1][4 + i2] = __builtin_amdgcn_mfma_f32_16x16x32_f16(af[1], bf, acc[1][4 + i2], 0, 0, 0);
            acc[2][4 + i2] = __builtin_amdgcn_mfma_f32_16x16x32_f16(af[2], bf, acc[2][4 + i2], 0, 0, 0);
            acc[3][4 + i2] = __builtin_amdgcn_mfma_f32_16x16x32_f16(af[3], bf, acc[3][4 + i2], 0, 0, 0);
        }
        if (ks < 15) {
            #pragma unroll
            for (int q = 0; q < 4; ++q) {
                int s = tid + 512 * q;
                int nl = s >> 2, gg = s & 3;
                int line = nl >> 1;
                int pos = (gg + 4 * (nl & 1)) ^ (line & 7);
                *(float4*)(smem + LDS_B0 + line * 128 + pos * 16) = st[q];
            }
        }
        __syncthreads();
    }

    // ---- epilogue: params -> LDS (m-halves), fused spline ----
    #pragma unroll
    for (int mh = 0; mh < 2; ++mh) {
        __syncthreads();
        #pragma unroll
        for (int mt2 = 0; mt2 < 2; ++mt2) {
            #pragma unroll
            for (int i = 0; i < 8; ++i) {
                int ntile = w + 8 * i;
                if (ntile < 58) {               // skip n >= 928 padding
                    int n = ntile * 16 + l15;
                    int prow = mt2 * 16 + g * 4;
                    #pragma unroll
                    for (int r = 0; r < 4; ++r) {
                        *(float*)(smem + ((prow + r) * PSTR + n) * 4) =
                            acc[mh * 2 + mt2][i][r];
                    }
                }
            }
        }
        __syncthreads();

        int row_l = tid >> 4;
        int grow = row0 + mh * 32 + row_l;
        float lads[2], ots[2];
        #pragma unroll
        for (int ff = 0; ff < 2; ++ff) {
            int f = (tid & 15) * 2 + ff;
            float p[PPF];
            #pragma unroll
            for (int j = 0; j < PPF; ++j)
                p[j] = *(const float*)(smem + (row_l * PSTR + f * PPF + j) * 4)
                       + sb2[f * PPF + j];
            float xv = x[(size_t)grow * 64 + 2 * f];
            float yo, lo, oo;
            rqs_one(p, xv, yo, lo, oo);
            out[(size_t)grow * 64 + 2 * f] = yo;
            lads[ff] = lo;
            ots[ff] = oo;
        }
        float ladp = lads[0] + lads[1];
        float otp  = ots[0] + ots[1];
        #pragma unroll
        for (int m = 1; m < 16; m <<= 1) {
            ladp += __shfl_xor(ladp, m);
            otp  += __shfl_xor(otp, m);
        }
        if ((tid & 15) == 0) {
            lad_out[grow] = ladp;
            ot_out[grow]  = otp;
        }
    }
}

extern "C" void kernel_launch(void* const* d_in, const int* in_sizes, int n_in,
                              void* d_out, int out_size, void* d_ws, size_t ws_size,
                              hipStream_t stream) {
    const float* x  = (const float*)d_in[0];
    const float* W1 = (const float*)d_in[1];
    const float* b1 = (const float*)d_in[2];
    const float* W2 = (const float*)d_in[3];
    const float* b2 = (const float*)d_in[4];
    float* out = (float*)d_out;
    float* lad = out + (size_t)NROWS * 64;
    float* otc = lad + NROWS;

    char* wsb = (char*)d_ws;
    _Float16* W2T = (_Float16*)wsb;
    _Float16* W1T = (_Float16*)(wsb + W1T_OFF);

    hipLaunchKernelGGL(prep_w2, dim3(512), dim3(256), 0, stream, W2, W2T);
    hipLaunchKernelGGL(prep_w1, dim3(64), dim3(256), 0, stream, W1, W1T);
    hipLaunchKernelGGL(flow_main, dim3(NBLK), dim3(THREADS), 0, stream,
                       x, b1, b2, W2T, W1T, out, lad, otc);
}